// Round 2
// baseline (263.433 us; speedup 1.0000x reference)
//
#include <hip/hip_runtime.h>

#define LOG2E 1.44269504088896340736f
#define DM 1536
#define LL  2048
#define NN  16
#define NCH 64     // chunks per row = lanes per wave
#define CL  32     // LL / NCH

__device__ __forceinline__ float fexp2(float v){ return __builtin_amdgcn_exp2f(v); }
__device__ __forceinline__ float frcp(float v){ return __builtin_amdgcn_rcpf(v); }

// B,C: [b][n][t] -> Bt[((b*CL + (t&31))*NCH + (t>>5))*NN + n]
// so that at inner step r, a wave's 64 lanes (chunks) read one contiguous
// 4 KB slab with coalesced float4 loads. Output-indexed: writes coalesced,
// scattered reads absorbed by L2 (inputs are only 256 KB each).
__global__ __launch_bounds__(256) void transpose_bc(
        const float* __restrict__ Bm, const float* __restrict__ Cm,
        float* __restrict__ Bt, float* __restrict__ Ct){
    int o = blockIdx.x*256 + threadIdx.x;        // 2*16*2048 = 65536 outputs
    int n = o & 15, c = (o>>4) & 63, r = (o>>10) & 31, b = o>>15;
    int i = (b*NN + n)*LL + c*CL + r;
    Bt[o] = Bm[i];
    Ct[o] = Cm[i];
}

// One wave per (b,d) row; lane = chunk (64 chunks x 32 steps). Each thread
// carries all 16 states in registers -> y is thread-local, no per-step
// cross-lane ops. Chunk composition: once-per-kernel Kogge-Stone wave scan
// on the affine operator (P,G): combine(left,self) = (P*Pl, fma(P,Gl,G)).
// block=256 (4 rows) so waves sharing b hit the same B/C slabs in L1.
__global__ __launch_bounds__(256, 3) void ssm_scan(
    const float* __restrict__ x, const float* __restrict__ delta,
    const float* __restrict__ A, const float* __restrict__ Dv,
    const float* __restrict__ z, const float* __restrict__ Bt,
    const float* __restrict__ Ct, float* __restrict__ out)
{
    const int lane = threadIdx.x & 63;
    const int row  = blockIdx.x*4 + (threadIdx.x >> 6);   // b*DM + d
    const int b    = row / DM;
    const int d    = row - b*DM;

    float A2[NN];
#pragma unroll
    for (int n=0;n<NN;++n) A2[n] = A[d*NN+n] * LOG2E;     // exp(dA)=exp2(d*A2)

    const long  base = (long)row*LL + lane*CL;
    const float* dp = delta + base;
    const float* xp = x + base;
    const float* zp = z + base;
    const float* bq = Bt + (long)b*(CL*NCH*NN) + lane*NN; // + r*1024 per step
    const float* cq = Ct + (long)b*(CL*NCH*NN) + lane*NN;

    // ---- phase 1: local scan with h0=0 -> G; P = exp2(A2 * sum(delta))
    float G[NN];
#pragma unroll
    for (int n=0;n<NN;++n) G[n] = 0.f;
    float dsum = 0.f;
    for (int i=0;i<CL;i+=4){
        const float4 d4 = *(const float4*)(dp+i);
        const float4 x4 = *(const float4*)(xp+i);
        const float dd[4]={d4.x,d4.y,d4.z,d4.w};
        const float xx[4]={x4.x,x4.y,x4.z,x4.w};
#pragma unroll
        for (int j=0;j<4;++j){
            const float* br = bq + (i+j)*(NCH*NN);
            const float4 b0=*(const float4*)(br),   b1=*(const float4*)(br+4),
                         b2=*(const float4*)(br+8), b3=*(const float4*)(br+12);
            const float bb[16]={b0.x,b0.y,b0.z,b0.w, b1.x,b1.y,b1.z,b1.w,
                                b2.x,b2.y,b2.z,b2.w, b3.x,b3.y,b3.z,b3.w};
            const float dx = dd[j]*xx[j];
            dsum += dd[j];
#pragma unroll
            for (int n=0;n<NN;++n){
                const float a = fexp2(dd[j]*A2[n]);
                G[n] = __builtin_fmaf(a, G[n], bb[n]*dx);
            }
        }
    }
    float P[NN];
#pragma unroll
    for (int n=0;n<NN;++n) P[n] = fexp2(dsum*A2[n]);

    // ---- phase 2: inclusive wave scan over chunks, then exclusive shift
#pragma unroll
    for (int s=1;s<64;s<<=1){
#pragma unroll
        for (int n=0;n<NN;++n){
            const float pl = __shfl_up(P[n], s);
            const float gl = __shfl_up(G[n], s);
            if (lane >= s){
                G[n] = __builtin_fmaf(P[n], gl, G[n]);
                P[n] *= pl;
            }
        }
    }
    float h[NN];
#pragma unroll
    for (int n=0;n<NN;++n){
        const float gp = __shfl_up(G[n], 1);
        h[n] = (lane==0) ? 0.f : gp;
    }

    // ---- phase 3: re-scan with true h_start; fused (y+x*D)*silu(z)
    const float Dd = Dv[d];
    float* op = out + base;
    for (int i=0;i<CL;i+=4){
        const float4 d4 = *(const float4*)(dp+i);
        const float4 x4 = *(const float4*)(xp+i);
        const float4 z4 = *(const float4*)(zp+i);
        const float dd[4]={d4.x,d4.y,d4.z,d4.w};
        const float xx[4]={x4.x,x4.y,x4.z,x4.w};
        const float zz[4]={z4.x,z4.y,z4.z,z4.w};
        float yv[4];
#pragma unroll
        for (int j=0;j<4;++j){
            const float* br = bq + (i+j)*(NCH*NN);
            const float* cr = cq + (i+j)*(NCH*NN);
            const float4 b0=*(const float4*)(br),   b1=*(const float4*)(br+4),
                         b2=*(const float4*)(br+8), b3=*(const float4*)(br+12);
            const float4 c0=*(const float4*)(cr),   c1=*(const float4*)(cr+4),
                         c2=*(const float4*)(cr+8), c3=*(const float4*)(cr+12);
            const float bb[16]={b0.x,b0.y,b0.z,b0.w, b1.x,b1.y,b1.z,b1.w,
                                b2.x,b2.y,b2.z,b2.w, b3.x,b3.y,b3.z,b3.w};
            const float cc[16]={c0.x,c0.y,c0.z,c0.w, c1.x,c1.y,c1.z,c1.w,
                                c2.x,c2.y,c2.z,c2.w, c3.x,c3.y,c3.z,c3.w};
            const float dx = dd[j]*xx[j];
            float y0=0.f, y1=0.f, y2=0.f, y3=0.f;
#pragma unroll
            for (int n=0;n<NN;n+=4){
                const float a0=fexp2(dd[j]*A2[n+0]);
                h[n+0]=__builtin_fmaf(a0,h[n+0],bb[n+0]*dx); y0=__builtin_fmaf(h[n+0],cc[n+0],y0);
                const float a1=fexp2(dd[j]*A2[n+1]);
                h[n+1]=__builtin_fmaf(a1,h[n+1],bb[n+1]*dx); y1=__builtin_fmaf(h[n+1],cc[n+1],y1);
                const float a2=fexp2(dd[j]*A2[n+2]);
                h[n+2]=__builtin_fmaf(a2,h[n+2],bb[n+2]*dx); y2=__builtin_fmaf(h[n+2],cc[n+2],y2);
                const float a3=fexp2(dd[j]*A2[n+3]);
                h[n+3]=__builtin_fmaf(a3,h[n+3],bb[n+3]*dx); y3=__builtin_fmaf(h[n+3],cc[n+3],y3);
            }
            const float y = (y0+y1)+(y2+y3);
            const float sig = frcp(1.f + fexp2(-zz[j]*LOG2E));
            yv[j] = (y + xx[j]*Dd) * (zz[j]*sig);
        }
        float4 o4 = {yv[0], yv[1], yv[2], yv[3]};
        *(float4*)(op+i) = o4;
    }
}

extern "C" void kernel_launch(void* const* d_in, const int* in_sizes, int n_in,
                              void* d_out, int out_size, void* d_ws, size_t ws_size,
                              hipStream_t stream) {
    const float* x     = (const float*)d_in[0];
    const float* delta = (const float*)d_in[1];
    const float* A     = (const float*)d_in[2];
    const float* B     = (const float*)d_in[3];
    const float* C     = (const float*)d_in[4];
    const float* Dv    = (const float*)d_in[5];
    const float* z     = (const float*)d_in[6];
    float* out = (float*)d_out;

    float* Bt = (float*)d_ws;                  // 65536 floats = 256 KB
    float* Ct = Bt + 2*LL*NN;                  // next 256 KB

    transpose_bc<<<dim3(256), dim3(256), 0, stream>>>(B, C, Bt, Ct);
    ssm_scan<<<dim3((2*DM)/4), dim3(256), 0, stream>>>(x, delta, A, Dv, z, Bt, Ct, out);
}

// Round 3
// 183.511 us; speedup vs baseline: 1.4355x; 1.4355x over previous
//
#include <hip/hip_runtime.h>

#define LOG2E 1.44269504088896340736f
#define DM 1536
#define LL  2048
#define NN  16
#define NCH 64     // chunks per row = lanes per wave
#define CL  32     // LL / NCH

__device__ __forceinline__ float fexp2(float v){ return __builtin_amdgcn_exp2f(v); }
__device__ __forceinline__ float frcp(float v){ return __builtin_amdgcn_rcpf(v); }

__device__ __forceinline__ void load16(const float* __restrict__ p, float* v){
    const float4 a=*(const float4*)p,     b=*(const float4*)(p+4),
                 c=*(const float4*)(p+8), d=*(const float4*)(p+12);
    v[0]=a.x; v[1]=a.y; v[2]=a.z; v[3]=a.w;
    v[4]=b.x; v[5]=b.y; v[6]=b.z; v[7]=b.w;
    v[8]=c.x; v[9]=c.y; v[10]=c.z; v[11]=c.w;
    v[12]=d.x; v[13]=d.y; v[14]=d.z; v[15]=d.w;
}

// B,C: [b][n][t] -> Bt[((b*32 + (t&31))*64 + (t>>5))*16 + n]
// At step r a wave's 64 lanes (chunks) read one contiguous 4 KB slab.
__global__ __launch_bounds__(256) void transpose_bc(
        const float* __restrict__ Bm, const float* __restrict__ Cm,
        float* __restrict__ Bt, float* __restrict__ Ct){
    int o = blockIdx.x*256 + threadIdx.x;        // 65536 outputs
    int n = o & 15, c = (o>>4) & 63, r = (o>>10) & 31, b = o>>15;
    int i = (b*NN + n)*LL + c*CL + r;
    Bt[o] = Bm[i];
    Ct[o] = Cm[i];
}

// Block = 4 waves, wave = one (b,d) row. Lane = chunk (64 x 32 steps),
// thread owns all 16 states -> no per-step cross-lane ops.
// x/delta staged via LDS with XOR swizzle slot(r,c)=r*64+(c^r):
//   - staging writes (t-major, coalesced global reads) conflict-free
//   - per-step reads (fixed r, c=lane) conflict-free
// Phase 3 overwrites x-slot with (y + x*D); coalesced epilogue applies silu(z).
// 64 KB LDS/block -> 2 blocks/CU. No __syncthreads (wave-private LDS rows).
__global__ __launch_bounds__(256, 2) void ssm_scan(
    const float* __restrict__ x, const float* __restrict__ delta,
    const float* __restrict__ A, const float* __restrict__ Dv,
    const float* __restrict__ z, const float* __restrict__ Bt,
    const float* __restrict__ Ct, float* __restrict__ out)
{
    __shared__ float sd[4][CL*64];   // delta, transposed+swizzled
    __shared__ float sx[4][CL*64];   // x, later (y + x*D)

    const int lane = threadIdx.x & 63;
    const int w    = threadIdx.x >> 6;
    const int row  = blockIdx.x*4 + w;           // b*DM + d
    const int b    = (row >= DM) ? 1 : 0;
    const int d    = row - b*DM;

    float* sdw = sd[w];
    float* sxw = sx[w];

    const long base = (long)row*LL;
    const float* gd = delta + base;
    const float* gx = x + base;

    // ---- stage x, delta (coalesced float4 reads, conflict-free LDS writes)
    for (int k = 0; k < LL; k += 256){
        const int t0 = k + lane*4;
        const float4 dv = *(const float4*)(gd + t0);
        const float4 xv = *(const float4*)(gx + t0);
        const float dd[4]={dv.x,dv.y,dv.z,dv.w};
        const float xx[4]={xv.x,xv.y,xv.z,xv.w};
#pragma unroll
        for (int j=0;j<4;++j){
            const int t = t0 + j;
            const int r = t & 31, c = t >> 5;
            const int a = r*64 + (c ^ r);
            sdw[a] = dd[j];
            sxw[a] = xx[j];
        }
    }

    float A2[NN];
#pragma unroll
    for (int n=0;n<NN;++n) A2[n] = A[d*NN+n] * LOG2E;   // exp(dA)=exp2(d*A2)

    const float* bq = Bt + (long)b*(CL*NCH*NN) + lane*NN;  // + r*1024 per step
    const float* cq = Ct + (long)b*(CL*NCH*NN) + lane*NN;

    // ---- phase 1: local scan h0=0 -> G; P = exp2(A2 * sum(delta))
    float G[NN];
#pragma unroll
    for (int n=0;n<NN;++n) G[n] = 0.f;
    float dsum = 0.f;
#pragma unroll 2
    for (int r=0;r<CL;++r){
        const int a = r*64 + (lane ^ r);
        const float d_r = sdw[a];
        const float x_r = sxw[a];
        float bb[16];
        load16(bq + r*(NCH*NN), bb);
        dsum += d_r;
        const float dx = d_r * x_r;
#pragma unroll
        for (int n=0;n<NN;++n){
            const float e = fexp2(d_r*A2[n]);
            G[n] = __builtin_fmaf(e, G[n], bb[n]*dx);
        }
    }
    float P[NN];
#pragma unroll
    for (int n=0;n<NN;++n) P[n] = fexp2(dsum*A2[n]);

    // ---- phase 2: inclusive Kogge-Stone wave scan over chunks, then shift
#pragma unroll
    for (int s=1;s<64;s<<=1){
#pragma unroll
        for (int n=0;n<NN;++n){
            const float pl = __shfl_up(P[n], s);
            const float gl = __shfl_up(G[n], s);
            if (lane >= s){
                G[n] = __builtin_fmaf(P[n], gl, G[n]);
                P[n] *= pl;
            }
        }
    }
    float h[NN];
#pragma unroll
    for (int n=0;n<NN;++n){
        const float gp = __shfl_up(G[n], 1);
        h[n] = (lane==0) ? 0.f : gp;
    }

    // ---- phase 3: re-scan with true h_start; stash (y + x*D) into x-slot
    const float Dd = Dv[d];
#pragma unroll 2
    for (int r=0;r<CL;++r){
        const int a = r*64 + (lane ^ r);
        const float d_r = sdw[a];
        const float x_r = sxw[a];
        float bb[16], cc[16];
        load16(bq + r*(NCH*NN), bb);
        load16(cq + r*(NCH*NN), cc);
        const float dx = d_r * x_r;
        float y0=0.f, y1=0.f, y2=0.f, y3=0.f;
#pragma unroll
        for (int n=0;n<NN;n+=4){
            const float e0=fexp2(d_r*A2[n+0]);
            h[n+0]=__builtin_fmaf(e0,h[n+0],bb[n+0]*dx); y0=__builtin_fmaf(h[n+0],cc[n+0],y0);
            const float e1=fexp2(d_r*A2[n+1]);
            h[n+1]=__builtin_fmaf(e1,h[n+1],bb[n+1]*dx); y1=__builtin_fmaf(h[n+1],cc[n+1],y1);
            const float e2=fexp2(d_r*A2[n+2]);
            h[n+2]=__builtin_fmaf(e2,h[n+2],bb[n+2]*dx); y2=__builtin_fmaf(h[n+2],cc[n+2],y2);
            const float e3=fexp2(d_r*A2[n+3]);
            h[n+3]=__builtin_fmaf(e3,h[n+3],bb[n+3]*dx); y3=__builtin_fmaf(h[n+3],cc[n+3],y3);
        }
        const float y = (y0+y1)+(y2+y3);
        sxw[a] = __builtin_fmaf(x_r, Dd, y);     // (y + x*D), silu applied later
    }

    // ---- epilogue: stream z once, fully coalesced float4 in/out
    const float* gz = z + base;
    float* go = out + base;
    for (int k=0;k<LL;k+=256){
        const int t0 = k + lane*4;
        const float4 zv = *(const float4*)(gz + t0);
        const float zz[4]={zv.x,zv.y,zv.z,zv.w};
        float o[4];
#pragma unroll
        for (int j=0;j<4;++j){
            const int t = t0 + j;
            const int r = t & 31, c = t >> 5;
            const float yd = sxw[r*64 + (c ^ r)];
            const float sig = frcp(1.f + fexp2(-zz[j]*LOG2E));
            o[j] = yd * (zz[j]*sig);
        }
        float4 o4 = {o[0],o[1],o[2],o[3]};
        *(float4*)(go + t0) = o4;
    }
}

extern "C" void kernel_launch(void* const* d_in, const int* in_sizes, int n_in,
                              void* d_out, int out_size, void* d_ws, size_t ws_size,
                              hipStream_t stream) {
    const float* x     = (const float*)d_in[0];
    const float* delta = (const float*)d_in[1];
    const float* A     = (const float*)d_in[2];
    const float* B     = (const float*)d_in[3];
    const float* C     = (const float*)d_in[4];
    const float* Dv    = (const float*)d_in[5];
    const float* z     = (const float*)d_in[6];
    float* out = (float*)d_out;

    float* Bt = (float*)d_ws;                  // 65536 floats = 256 KB
    float* Ct = Bt + 2*LL*NN;                  // next 256 KB

    transpose_bc<<<dim3(256), dim3(256), 0, stream>>>(B, C, Bt, Ct);
    ssm_scan<<<dim3((2*DM)/4), dim3(256), 0, stream>>>(x, delta, A, Dv, z, Bt, Ct, out);
}